// Round 6
// baseline (63.005 us; speedup 1.0000x reference)
//
#include <hip/hip_runtime.h>

#define NB 8
#define NL 512
#define ND 128

constexpr float CEXP = 2.8853900817779268f;   // 2*log2(e): exp2(CEXP*x) = e^{2x}

typedef float v2f __attribute__((ext_vector_type(2)));

// wpack: transpose+d4-pack weights (wp[(d>>2)*512 + e*4 + (d&3)] = w[e][d])
// so qk's weight loads are lane-coalesced.
__global__ __launch_bounds__(256) void wpack_kernel(
    const float* __restrict__ uw, const float* __restrict__ vw,
    float* __restrict__ uwp, float* __restrict__ vwp) {
  const int m = blockIdx.x >> 4;                        // 0: uw, 1: vw
  const int t = (blockIdx.x & 15) * 256 + threadIdx.x;  // 0..4095
  const float4* src = (const float4*)(m ? vw : uw);
  float4* dst = (float4*)(m ? vwp : uwp);
  const int e = t >> 5, d4 = t & 31;
  float4 v = src[e * 32 + d4];       // w[e][4d4..+3], coalesced read
  dst[d4 * 128 + e] = v;             // wp[d4][e][4]
}

// Kernel A: q = inp @ uw^T, k = inp @ vw^T.
//  eqp = exp2(CEXP*q), d4-packed-transposed [b][e4][l][4]  (VMEM stream)
//  ekq = exp2(CEXP*k), slot-interleaved [b][tile][e][8] with slot order
//        (i0,i4,i1,i5,i2,i6,i3,i7) so attn reads aligned v2f pairs.
// inp rows are read via uniform s_loads (no LDS staging, no barrier).
__global__ __launch_bounds__(256) void qk_kernel(
    const float* __restrict__ inp, const float* __restrict__ uwp,
    const float* __restrict__ vwp, float* __restrict__ eqp,
    float* __restrict__ ekq) {
  __shared__ float qt[128][9];    // pad 9: conflict-free transpose
  const int b = blockIdx.x & 7;   // batch-per-XCD affinity (matches attn)
  const int l0 = (blockIdx.x >> 3) * 8;
  const int tid = threadIdx.x;

  const int e = tid & 127;
  const int half = tid >> 7;                 // 0 -> q (uw), 1 -> k (vw)
  const float* xrow = inp + (b * NL + l0) * ND;   // uniform base -> s_load
  const float4* W4 = (const float4*)(half ? vwp : uwp) + e;  // coalesced
  float acc[8];
#pragma unroll
  for (int r = 0; r < 8; ++r) acc[r] = 0.f;
  float4 w = W4[0];
  for (int d4 = 0; d4 < 32; ++d4) {
    float4 wn = W4[(size_t)((d4 + 1 > 31) ? 31 : d4 + 1) * 128];
#pragma unroll
    for (int r = 0; r < 8; ++r) {
      // uniform address -> scalar loads, broadcast as SGPR operands
      float4 x = *((const float4*)&xrow[r * ND + 4 * d4]);
      acc[r] = fmaf(w.x, x.x, acc[r]);
      acc[r] = fmaf(w.y, x.y, acc[r]);
      acc[r] = fmaf(w.z, x.z, acc[r]);
      acc[r] = fmaf(w.w, x.w, acc[r]);
    }
    w = wn;
  }
  if (half) {
    float* ekb = ekq + ((size_t)(b * 64 + (l0 >> 3)) * 128 + e) * 8;
#pragma unroll
    for (int r = 0; r < 8; ++r) {
      const int slot = (r & 3) * 2 + (r >> 2);
      ekb[slot] = __builtin_amdgcn_exp2f(CEXP * acc[r]);  // 32B/thread
    }
  } else {
#pragma unroll
    for (int r = 0; r < 8; ++r)
      qt[e][r] = __builtin_amdgcn_exp2f(CEXP * acc[r]);
  }
  __syncthreads();
  {
    // all 256 threads: thread -> (e4 = tid>>3, r = tid&7)
    const int e4 = tid >> 3, r = tid & 7;
    float4 v = make_float4(qt[4 * e4][r], qt[4 * e4 + 1][r],
                           qt[4 * e4 + 2][r], qt[4 * e4 + 3][r]);
    ((float4*)eqp)[(b * 32 + e4) * NL + l0 + r] = v;
  }
}

// Kernel B: 8-row i-tile, 512 threads, 512 blocks — the round-0 winner
// with ONE change: the eq stream is register-double-buffered in 8-d4
// chunks, so the score loop has NO vmcnt wait inside its dependence
// window (prefetch depth 8 d4-iters ~ 2300cy >> L2 latency ~300cy; the
// old eA/eB/eC rotation nominally covered 2 iters but the scheduler
// commonly degrades loop-carried rotations to ~1-iter issue distance).
// Evidence trail: busy capped ~53% at 8/16/32 waves/CU (occupancy ruled
// out), LDS-vs-K$ swap neutral (R5), busy-time == pure-VALU cycle model
// -> the 47% idle must come from the one stream never touched: eq VMEM.
// ALL uniform addresses derive from blockIdx (rounds 1/2 lesson).
__global__ __launch_bounds__(512, 4) void attn_kernel(
    const float* __restrict__ inp, const float* __restrict__ aw,
    const float* __restrict__ eqp, const float* __restrict__ ekq,
    float* __restrict__ out, float* __restrict__ attn) {
  __shared__ v2f red[8][8][64];        // PV partials (32KB)
  __shared__ float attn_lds[8][512];   // 16KB
  __shared__ float rsum[8][8];

  const int b = blockIdx.x & 7;       // batch-per-XCD affinity
  const int i0 = (blockIdx.x >> 3) * 8;
  const int tid = threadIdx.x;
  const int lane = tid & 63;
  const int wid = tid >> 6;

  // ---- score stage: thread owns column j = tid; 8 rows as 4 v2f pairs
  v2f acc04 = {0.f, 0.f}, acc15 = {0.f, 0.f};
  v2f acc26 = {0.f, 0.f}, acc37 = {0.f, 0.f};
  const v2f ONE2 = {1.f, 1.f};
  const float4* eq4 = (const float4*)eqp + (size_t)(b * 32) * NL + tid;
  const float4* aw4 = (const float4*)aw;
  // uniform pointer: pairs (e_i0,e_i4),(e_i1,e_i5),(e_i2,e_i6),(e_i3,e_i7)
  const v2f* ekq2 =
      (const v2f*)(ekq + (size_t)(b * 64 + (i0 >> 3)) * 128 * 8);

// one 8-d4 chunk of the score loop; EQR is a register buffer (8 float4,
// compile-time indexed), C0 the chunk base (runtime OK: only addresses).
#define SCORE_CHUNK(EQR, C0)                                              \
  {                                                                       \
    _Pragma("unroll")                                                     \
    for (int d8 = 0; d8 < 8; ++d8) {                                      \
      const int d4 = (C0) * 8 + d8;                                       \
      const float4 eqv = EQR[d8];                                         \
      const float4 na4 = aw4[d4];               /* uniform -> s_load */   \
      _Pragma("unroll")                                                   \
      for (int dd = 0; dd < 4; ++dd) {                                    \
        const int d = 4 * d4 + dd;                                        \
        const float eqs = (dd == 0) ? eqv.x : (dd == 1) ? eqv.y           \
                         : (dd == 2) ? eqv.z : eqv.w;                     \
        const float na = (dd == 0) ? na4.x : (dd == 1) ? na4.y            \
                        : (dd == 2) ? na4.z : na4.w;                      \
        v2f e01 = ekq2[d * 4 + 0];   /* uniform -> SGPR pair */           \
        v2f e23 = ekq2[d * 4 + 1];                                        \
        v2f e45 = ekq2[d * 4 + 2];                                        \
        v2f e67 = ekq2[d * 4 + 3];                                        \
        v2f eq2 = {eqs, eqs};                                             \
        /* p = 1 + eq*ek; tanh = 1 - 2/p; "+1" softmax-invariant, the */  \
        /* -2 is folded into the exp2 constant below. */                  \
        v2f Pa = __builtin_elementwise_fma(eq2, e01, ONE2); /* (0,4) */   \
        v2f Pb = __builtin_elementwise_fma(eq2, e23, ONE2); /* (1,5) */   \
        v2f Pc = __builtin_elementwise_fma(eq2, e45, ONE2); /* (2,6) */   \
        v2f Pd = __builtin_elementwise_fma(eq2, e67, ONE2); /* (3,7) */   \
        v2f M1 = Pa * Pb;    /* (p0p1, p4p5) */                           \
        v2f M2 = Pc * Pd;    /* (p2p3, p6p7) */                           \
        v2f Q = M1 * M2;     /* (p0123, p4567) */                         \
        v2f NR = {na * __builtin_amdgcn_rcpf(Q.x),                        \
                  na * __builtin_amdgcn_rcpf(Q.y)};                       \
        v2f T = NR * M2;     /* (na/p01, na/p45) */                       \
        v2f U = NR * M1;     /* (na/p23, na/p67) */                       \
        acc04 = __builtin_elementwise_fma(T, Pb, acc04);                  \
        acc15 = __builtin_elementwise_fma(T, Pa, acc15);                  \
        acc26 = __builtin_elementwise_fma(U, Pd, acc26);                  \
        acc37 = __builtin_elementwise_fma(U, Pc, acc37);                  \
      }                                                                   \
    }                                                                     \
  }

  // chunked register double-buffer for the eq stream: compute chunk c
  // while chunk c+1's 8 float4 loads are in flight. Buffers explicitly
  // named; the 2-iter runtime t-loop keeps all indices compile-time.
  float4 eqA[8], eqB[8];
#pragma unroll
  for (int k = 0; k < 8; ++k) eqA[k] = eq4[(size_t)k * NL];       // chunk 0
  for (int t = 0; t < 2; ++t) {
    const int c0 = 2 * t;
#pragma unroll
    for (int k = 0; k < 8; ++k)                                   // chunk c0+1
      eqB[k] = eq4[(size_t)((c0 + 1) * 8 + k) * NL];
    SCORE_CHUNK(eqA, c0)
    if (t < 1) {
#pragma unroll
      for (int k = 0; k < 8; ++k)                                 // chunk c0+2
        eqA[k] = eq4[(size_t)((c0 + 2) * 8 + k) * NL];
    }
    SCORE_CHUNK(eqB, (c0 + 1))
  }
#undef SCORE_CHUNK

  float acc[8] = {acc04.x, acc15.x, acc26.x, acc37.x,
                  acc04.y, acc15.y, acc26.y, acc37.y};

  // ---- softmax over j; score = -2*acc (fold -2 into exp2 constant);
  // no max-subtraction: |exp2 arg| <= ~26, safe in f32.
  float sinv[8], ex[8];
#pragma unroll
  for (int i = 0; i < 8; ++i) {
    float e = __builtin_amdgcn_exp2f(acc[i] * (-CEXP));
    ex[i] = e;
    float s = e;
#pragma unroll
    for (int off = 32; off; off >>= 1) s += __shfl_xor(s, off);
    if (lane == 0) rsum[wid][i] = s;
  }
  __syncthreads();
#pragma unroll
  for (int i = 0; i < 8; ++i) {
    float s = ((rsum[0][i] + rsum[1][i]) + (rsum[2][i] + rsum[3][i])) +
              ((rsum[4][i] + rsum[5][i]) + (rsum[6][i] + rsum[7][i]));
    sinv[i] = __builtin_amdgcn_rcpf(s);
  }

  float* attnb = attn + (size_t)(b * NL + i0) * NL;
#pragma unroll
  for (int i = 0; i < 8; ++i) {
    float a = ex[i] * sinv[i];
    attn_lds[i][tid] = a;
    attnb[i * NL + tid] = a;           // coalesced
  }
  __syncthreads();

  // ---- PV: wave w owns j in [64w, 64w+64); lane owns v2f d-pair
  v2f po[8];
#pragma unroll
  for (int i = 0; i < 8; ++i) po[i] = (v2f){0.f, 0.f};
  const v2f* inp2 = (const v2f*)(inp + b * NL * ND);
  for (int jj4 = 0; jj4 < 16; ++jj4) {
    const int jc = wid * 64 + jj4 * 4;
    v2f x0 = inp2[(jc + 0) * 64 + lane];   // coalesced (L2-resident)
    v2f x1 = inp2[(jc + 1) * 64 + lane];
    v2f x2 = inp2[(jc + 2) * 64 + lane];
    v2f x3 = inp2[(jc + 3) * 64 + lane];
#pragma unroll
    for (int i = 0; i < 8; ++i) {
      float4 a4 = *((const float4*)&attn_lds[i][jc]);   // uniform broadcast
      po[i] = __builtin_elementwise_fma((v2f){a4.x, a4.x}, x0, po[i]);
      po[i] = __builtin_elementwise_fma((v2f){a4.y, a4.y}, x1, po[i]);
      po[i] = __builtin_elementwise_fma((v2f){a4.z, a4.z}, x2, po[i]);
      po[i] = __builtin_elementwise_fma((v2f){a4.w, a4.w}, x3, po[i]);
    }
  }
#pragma unroll
  for (int i = 0; i < 8; ++i) red[wid][i][lane] = po[i];
  __syncthreads();
  {
    const int i2 = wid, dl = lane;
    v2f s = red[0][i2][dl];
#pragma unroll
    for (int p = 1; p < 8; ++p) s += red[p][i2][dl];
    *(v2f*)&out[(size_t)(b * NL + i0 + i2) * ND + dl * 2] = s;
  }
}

extern "C" void kernel_launch(void* const* d_in, const int* in_sizes, int n_in,
                              void* d_out, int out_size, void* d_ws,
                              size_t ws_size, hipStream_t stream) {
  const float* inp = (const float*)d_in[0];
  const float* uw = (const float*)d_in[1];
  const float* vw = (const float*)d_in[2];
  const float* aw = (const float*)d_in[3];
  float* out = (float*)d_out;
  float* attn = out + NB * NL * ND;        // tuple order: (out, attn)
  float* eqp = (float*)d_ws;               // [B][32][512][4] packed exp2 q
  float* ekq = eqp + NB * ND * NL;         // [B][64][128][8] slot-interleaved
  size_t need = (size_t)2 * NB * ND * NL * 4 + 32768 * 4;
  float* wp = (ws_size >= need) ? (ekq + NB * ND * NL) : (attn);
  float* uwp = wp;                 // 16384
  float* vwp = wp + 16384;         // 16384
  wpack_kernel<<<dim3(32), 256, 0, stream>>>(uw, vw, uwp, vwp);
  qk_kernel<<<dim3(NB * 64), 256, 0, stream>>>(inp, uwp, vwp, eqp, ekq);
  attn_kernel<<<dim3(NB * 64), 512, 0, stream>>>(inp, aw, eqp, ekq, out, attn);
}

// Round 7
// 55.754 us; speedup vs baseline: 1.1301x; 1.1301x over previous
//
#include <hip/hip_runtime.h>

#define NB 8
#define NL 512
#define ND 128

constexpr float CEXP = 2.8853900817779268f;   // 2*log2(e): exp2(CEXP*x) = e^{2x}

typedef float v2f __attribute__((ext_vector_type(2)));

// wpack: transpose+d4-pack weights (wp[(d>>2)*512 + e*4 + (d&3)] = w[e][d])
// so qk's weight loads are lane-coalesced.
__global__ __launch_bounds__(256) void wpack_kernel(
    const float* __restrict__ uw, const float* __restrict__ vw,
    float* __restrict__ uwp, float* __restrict__ vwp) {
  const int m = blockIdx.x >> 4;                        // 0: uw, 1: vw
  const int t = (blockIdx.x & 15) * 256 + threadIdx.x;  // 0..4095
  const float4* src = (const float4*)(m ? vw : uw);
  float4* dst = (float4*)(m ? vwp : uwp);
  const int e = t >> 5, d4 = t & 31;
  float4 v = src[e * 32 + d4];       // w[e][4d4..+3], coalesced read
  dst[d4 * 128 + e] = v;             // wp[d4][e][4]
}

// Kernel A: q = inp @ uw^T, k = inp @ vw^T.
//  eqp = exp2(CEXP*q), d4-packed-transposed [b][e4][l][4]  (VMEM stream)
//  ekq = exp2(CEXP*k), 4-row-tile interleaved [b][tile][e][4] with slot
//        order (i0,i2,i1,i3) so attn reads two aligned v2f pairs per d.
// inp rows are read via uniform s_loads (no LDS staging, no barrier).
__global__ __launch_bounds__(256) void qk_kernel(
    const float* __restrict__ inp, const float* __restrict__ uwp,
    const float* __restrict__ vwp, float* __restrict__ eqp,
    float* __restrict__ ekq) {
  __shared__ float qt[128][9];    // pad 9: conflict-free transpose
  const int b = blockIdx.x & 7;   // batch-per-XCD affinity (matches attn)
  const int l0 = (blockIdx.x >> 3) * 8;
  const int tid = threadIdx.x;

  const int e = tid & 127;
  const int half = tid >> 7;                 // 0 -> q (uw), 1 -> k (vw)
  const float* xrow = inp + (b * NL + l0) * ND;   // uniform base -> s_load
  const float4* W4 = (const float4*)(half ? vwp : uwp) + e;  // coalesced
  float acc[8];
#pragma unroll
  for (int r = 0; r < 8; ++r) acc[r] = 0.f;
  float4 w = W4[0];
  for (int d4 = 0; d4 < 32; ++d4) {
    float4 wn = W4[(size_t)((d4 + 1 > 31) ? 31 : d4 + 1) * 128];
#pragma unroll
    for (int r = 0; r < 8; ++r) {
      // uniform address -> scalar loads, broadcast as SGPR operands
      float4 x = *((const float4*)&xrow[r * ND + 4 * d4]);
      acc[r] = fmaf(w.x, x.x, acc[r]);
      acc[r] = fmaf(w.y, x.y, acc[r]);
      acc[r] = fmaf(w.z, x.z, acc[r]);
      acc[r] = fmaf(w.w, x.w, acc[r]);
    }
    w = wn;
  }
  if (half) {
    float ek[8];
#pragma unroll
    for (int r = 0; r < 8; ++r)
      ek[r] = __builtin_amdgcn_exp2f(CEXP * acc[r]);
    // two 4-row tiles: slots (i0,i2,i1,i3) within each tile
    float4 lo = make_float4(ek[0], ek[2], ek[1], ek[3]);
    float4 hi = make_float4(ek[4], ek[6], ek[5], ek[7]);
    float4* ekb = (float4*)ekq + (size_t)(b * 128 + (l0 >> 2)) * 128 + e;
    ekb[0] = lo;       // tile l0/4,   coalesced across e
    ekb[128] = hi;     // tile l0/4+1, coalesced across e
  } else {
#pragma unroll
    for (int r = 0; r < 8; ++r)
      qt[e][r] = __builtin_amdgcn_exp2f(CEXP * acc[r]);
  }
  __syncthreads();
  {
    // all 256 threads: thread -> (e4 = tid>>3, r = tid&7)
    const int e4 = tid >> 3, r = tid & 7;
    float4 v = make_float4(qt[4 * e4][r], qt[4 * e4 + 1][r],
                           qt[4 * e4 + 2][r], qt[4 * e4 + 3][r]);
    ((float4*)eqp)[(b * 32 + e4) * NL + l0 + r] = v;
  }
}

// Kernel B: 4-row i-tile, 256 threads, 1024 blocks, C=2 columns/thread
// (thread owns cols j=tid and j+256). WHY: across R0/R3/R5/R6 the ledger
// shows dur*VALUBusy conserved (~21us-units) with busy capped ~53% at
// >=4 waves/SIMD -> a shared pipe at 100%: the per-wave UNIFORM ek/aw
// broadcast (s_load or ds, both tried) at ~2.0 B per VALU-cycle per CU.
// Broadcast bytes scale with rows, VALU with rows*C -> only C changes
// the ratio. C=2 keeps VALU work identical (2 cols x (5pk+2rcp) = 72cy
// per 8 outputs, same as R0's 72) but HALVES broadcast to ~1.1 B/cy.
// Occupancy stays 4 waves/SIMD (4 blocks/CU). ALL uniform addresses
// derive from blockIdx only (R1/R2 lesson); eq keeps the shallow rolling
// prefetch (R6 lesson: deep reg-dbuf thrashes L2).
__global__ __launch_bounds__(256, 4) void attn_kernel(
    const float* __restrict__ inp, const float* __restrict__ aw,
    const float* __restrict__ eqp, const float* __restrict__ ekq,
    float* __restrict__ out, float* __restrict__ attn) {
  __shared__ v2f red[4][4][64];        // PV partials (8KB)
  __shared__ float attn_lds[4][512];   // 8KB
  __shared__ float rsum[4][4];

  const int b = blockIdx.x & 7;       // batch-per-XCD affinity
  const int i0 = (blockIdx.x >> 3) * 4;
  const int tid = threadIdx.x;
  const int lane = tid & 63;
  const int wid = tid >> 6;           // 0..3

  // ---- score stage: thread owns cols (tid, tid+256); 4 rows as 2 v2f
  v2f aA02 = {0.f, 0.f}, aA13 = {0.f, 0.f};   // col A = tid
  v2f aB02 = {0.f, 0.f}, aB13 = {0.f, 0.f};   // col B = tid+256
  const v2f ONE2 = {1.f, 1.f};
  const float4* eqA4 = (const float4*)eqp + (size_t)(b * 32) * NL + tid;
  const float4* eqB4 = eqA4 + 256;
  const float4* aw4 = (const float4*)aw;
  // uniform pointer: per d, pairs (e_i0,e_i2),(e_i1,e_i3)
  const v2f* ekq2 =
      (const v2f*)(ekq + (size_t)(b * 128 + (i0 >> 2)) * 128 * 4);
  float4 eA0 = eqA4[0], eA1 = eqA4[NL];
  float4 eB0 = eqB4[0], eB1 = eqB4[NL];
#pragma unroll 4
  for (int d4 = 0; d4 < 32; ++d4) {
    const int nf = (d4 + 2 > 31) ? 31 : d4 + 2;      // 2-deep prefetch
    float4 eA2 = eqA4[(size_t)nf * NL];
    float4 eB2 = eqB4[(size_t)nf * NL];
    float4 na4 = aw4[d4];                            // uniform -> s_load
#pragma unroll
    for (int dd = 0; dd < 4; ++dd) {
      const int d = 4 * d4 + dd;
      const float eqa = (dd == 0) ? eA0.x : (dd == 1) ? eA0.y
                       : (dd == 2) ? eA0.z : eA0.w;
      const float eqb = (dd == 0) ? eB0.x : (dd == 1) ? eB0.y
                       : (dd == 2) ? eB0.z : eB0.w;
      const float na = (dd == 0) ? na4.x : (dd == 1) ? na4.y
                      : (dd == 2) ? na4.z : na4.w;
      v2f e02 = ekq2[d * 2 + 0];   // uniform -> SGPR pair (rows 0,2)
      v2f e13 = ekq2[d * 2 + 1];   // rows 1,3
      v2f na2 = {na, na};
      // p = 1 + eq*ek; tanh = 1 - 2/p; "+1" terms softmax-invariant,
      // the -2 is folded into the exp2 constant below.
      {  // col A
        v2f qa = {eqa, eqa};
        v2f Pa = __builtin_elementwise_fma(qa, e02, ONE2);  // (p0,p2)
        v2f Pb = __builtin_elementwise_fma(qa, e13, ONE2);  // (p1,p3)
        v2f M = Pa * Pb;
        v2f NR = na2 * (v2f){__builtin_amdgcn_rcpf(M.x),
                             __builtin_amdgcn_rcpf(M.y)};
        aA02 = __builtin_elementwise_fma(NR, Pb, aA02);     // na/p0,na/p2
        aA13 = __builtin_elementwise_fma(NR, Pa, aA13);     // na/p1,na/p3
      }
      {  // col B
        v2f qb = {eqb, eqb};
        v2f Pa = __builtin_elementwise_fma(qb, e02, ONE2);
        v2f Pb = __builtin_elementwise_fma(qb, e13, ONE2);
        v2f M = Pa * Pb;
        v2f NR = na2 * (v2f){__builtin_amdgcn_rcpf(M.x),
                             __builtin_amdgcn_rcpf(M.y)};
        aB02 = __builtin_elementwise_fma(NR, Pb, aB02);
        aB13 = __builtin_elementwise_fma(NR, Pa, aB13);
      }
    }
    eA0 = eA1; eA1 = eA2;
    eB0 = eB1; eB1 = eB2;
  }
  float accA[4] = {aA02.x, aA13.x, aA02.y, aA13.y};   // rows 0..3, col A
  float accB[4] = {aB02.x, aB13.x, aB02.y, aB13.y};   // rows 0..3, col B

  // ---- softmax over j; score = -2*acc (fold -2 into exp2 constant);
  // no max-subtraction: |exp2 arg| <= ~26, safe in f32.
  float exA[4], exB[4], sinv[4];
#pragma unroll
  for (int i = 0; i < 4; ++i) {
    exA[i] = __builtin_amdgcn_exp2f(accA[i] * (-CEXP));
    exB[i] = __builtin_amdgcn_exp2f(accB[i] * (-CEXP));
    float s = exA[i] + exB[i];
#pragma unroll
    for (int off = 32; off; off >>= 1) s += __shfl_xor(s, off);
    if (lane == 0) rsum[wid][i] = s;
  }
  __syncthreads();
#pragma unroll
  for (int i = 0; i < 4; ++i) {
    float s = (rsum[0][i] + rsum[1][i]) + (rsum[2][i] + rsum[3][i]);
    sinv[i] = __builtin_amdgcn_rcpf(s);
  }

  float* attnb = attn + (size_t)(b * NL + i0) * NL;
#pragma unroll
  for (int i = 0; i < 4; ++i) {
    float a0 = exA[i] * sinv[i];
    float a1 = exB[i] * sinv[i];
    attn_lds[i][tid] = a0;
    attn_lds[i][tid + 256] = a1;
    attnb[i * NL + tid] = a0;          // coalesced
    attnb[i * NL + tid + 256] = a1;
  }
  __syncthreads();

  // ---- PV: wave w owns j in [128w, 128w+128); lane owns v2f d-pair
  v2f po[4];
#pragma unroll
  for (int i = 0; i < 4; ++i) po[i] = (v2f){0.f, 0.f};
  const v2f* inp2 = (const v2f*)(inp + b * NL * ND);
  for (int jj4 = 0; jj4 < 32; ++jj4) {
    const int jc = wid * 128 + jj4 * 4;
    v2f x0 = inp2[(jc + 0) * 64 + lane];   // coalesced (L2-resident)
    v2f x1 = inp2[(jc + 1) * 64 + lane];
    v2f x2 = inp2[(jc + 2) * 64 + lane];
    v2f x3 = inp2[(jc + 3) * 64 + lane];
#pragma unroll
    for (int i = 0; i < 4; ++i) {
      float4 a4 = *((const float4*)&attn_lds[i][jc]);   // uniform broadcast
      po[i] = __builtin_elementwise_fma((v2f){a4.x, a4.x}, x0, po[i]);
      po[i] = __builtin_elementwise_fma((v2f){a4.y, a4.y}, x1, po[i]);
      po[i] = __builtin_elementwise_fma((v2f){a4.z, a4.z}, x2, po[i]);
      po[i] = __builtin_elementwise_fma((v2f){a4.w, a4.w}, x3, po[i]);
    }
  }
#pragma unroll
  for (int i = 0; i < 4; ++i) red[wid][i][lane] = po[i];
  __syncthreads();
  {
    const int i2 = wid, dl = lane;     // all 4 waves: one row each
    v2f s = (red[0][i2][dl] + red[1][i2][dl]) +
            (red[2][i2][dl] + red[3][i2][dl]);
    *(v2f*)&out[(size_t)(b * NL + i0 + i2) * ND + dl * 2] = s;
  }
}

extern "C" void kernel_launch(void* const* d_in, const int* in_sizes, int n_in,
                              void* d_out, int out_size, void* d_ws,
                              size_t ws_size, hipStream_t stream) {
  const float* inp = (const float*)d_in[0];
  const float* uw = (const float*)d_in[1];
  const float* vw = (const float*)d_in[2];
  const float* aw = (const float*)d_in[3];
  float* out = (float*)d_out;
  float* attn = out + NB * NL * ND;        // tuple order: (out, attn)
  float* eqp = (float*)d_ws;               // [B][32][512][4] packed exp2 q
  float* ekq = eqp + NB * ND * NL;         // [B][128][128][4] tile-interleaved
  size_t need = (size_t)2 * NB * ND * NL * 4 + 32768 * 4;
  float* wp = (ws_size >= need) ? (ekq + NB * ND * NL) : (attn);
  float* uwp = wp;                 // 16384
  float* vwp = wp + 16384;         // 16384
  wpack_kernel<<<dim3(32), 256, 0, stream>>>(uw, vw, uwp, vwp);
  qk_kernel<<<dim3(NB * 64), 256, 0, stream>>>(inp, uwp, vwp, eqp, ekq);
  attn_kernel<<<dim3(NB * 128), 256, 0, stream>>>(inp, aw, eqp, ekq, out, attn);
}